// Round 9
// baseline (158.916 us; speedup 1.0000x reference)
//
#include <hip/hip_runtime.h>

// Signature-kernel MMD via Goursat PDE — round 10.
// Round-9 postmortem: coalesced dY reloads raised VALUBusy (72->78) but
// dur 92->95: net +insts, constraint unmoved. Plateau r2/r4/r8/r9 =
// 92-100us across 4 xr mechanisms; measured ~80 VALU-equiv/row vs 45
// static in all of them. pk-fp32 ruled out (m07: plain fma already at the
// 157TF rate -> no dual-pump; retro-explains r5's null). Last clean
// hypothesis: 2-col/lane state (ya+yb=32 + xr + state ~52+) sits AT the
// cap-64 boundary -> allocator reload/copy churn in every variant; pins
// made it worse (r3/r6/r7). Fix by SHRINKING STATE, not forcing regs.
// Round-10: 1 col/lane, two passes. Pass0 = cols 1..64; boundary column
// K[.][64] saved to LDS (masked ds_write, 1/row); pass1 = cols 65..127
// seeded from it (ds_read2_b32 broadcast). Per-lane: ya=16 floats + g +
// acc ~= 30 VGPR, truly resident. Row = 16 FMA + 7 DPP + 3 = ~26 VALU;
// no c1 cndmask, no dual chains. 254 pass-rows/task.

#define XY_BLOCKS 1024
#define TRI_BLOCKS 544
#define NBT (XY_BLOCKS + 2 * TRI_BLOCKS)        // 2112 blocks
#define DINC_PER 130048                         // 64*127*16 floats

template <int C, int RM, int BM, bool BC>
__device__ __forceinline__ float dpp0(float x) {
    return __builtin_bit_cast(float, __builtin_amdgcn_update_dpp(
        0, __builtin_bit_cast(int, x), C, RM, BM, BC));
}

// 64-lane inclusive prefix sum, pure VALU (6 dependent adds).
__device__ __forceinline__ float wave_scan_incl(float v) {
    v += dpp0<0x111, 0xf, 0xf, true>(v);   // row_shr:1
    v += dpp0<0x112, 0xf, 0xf, true>(v);   // row_shr:2
    v += dpp0<0x114, 0xf, 0xf, true>(v);   // row_shr:4
    v += dpp0<0x118, 0xf, 0xf, true>(v);   // row_shr:8
    v += dpp0<0x142, 0xa, 0xf, false>(v);  // row_bcast:15 -> rows 1,3
    v += dpp0<0x143, 0xc, 0xf, false>(v);  // row_bcast:31 -> rows 2,3
    return v;
}

// lane l gets lane l-1's x; lane 0 gets `oldv` (runtime value OK).
__device__ __forceinline__ float wave_shr1(float x, float oldv) {
    return __builtin_bit_cast(float, __builtin_amdgcn_update_dpp(
        __builtin_bit_cast(int, oldv), __builtin_bit_cast(int, x),
        0x138, 0xf, 0xf, false));          // wave_shr:1
}

// ---- kernel 1: path increments X,Y -> ws (dX at 0, dY at DINC_PER) ----
// (r8 version, pitch 2032 per path) + zeroes out[0] for fused reduce.
__global__ __launch_bounds__(256) void sig_diff(
    const float* __restrict__ X, const float* __restrict__ Y,
    float* __restrict__ dInc, float* __restrict__ out)
{
    if (blockIdx.x == 0 && threadIdx.x == 0) out[0] = 0.0f;
    int i = blockIdx.x * 256 + threadIdx.x;   // float4 id, 65024 total
    if (i >= 65024) return;
    int which = (i >= 32512) ? 1 : 0;
    int j = i - which * 32512;
    int a = j / 508;                          // 127*4 float4 per path
    int rq = j - a * 508;                     // r*4 + q
    const float* S = which ? Y : X;
    const float4* p = (const float4*)(S + a * 2048) + rq;
    float4 v0 = p[0], v1 = p[4];              // +16 floats = next row
    float4 d;
    d.x = v1.x - v0.x; d.y = v1.y - v0.y;
    d.z = v1.z - v0.z; d.w = v1.w - v0.w;
    ((float4*)dInc)[i] = d;
}

// ---- kernel 2: PDE, 1 col/lane, 2 passes. 2112 blocks * 4 waves. ----
__global__ __launch_bounds__(256, 8) void sig_pde10(
    const float* __restrict__ dInc, float* __restrict__ out)
{
    __shared__ float4 Xs4[508];            // dX path of row-index a (8128 B)
    __shared__ float colbuf[4][128];       // per-wave K[.][64] boundary col
    __shared__ float red[4];
    const int wid  = threadIdx.x >> 6;
    const int lane = threadIdx.x & 63;
    const int BT   = blockIdx.x;

    // block-uniform decode -> (gram g, a, b0); b = b0 + wave id
    int g, a, b0;
    if (BT < XY_BLOCKS) {                  // XY: dense 64x64
        g = 2; a = BT >> 4; b0 = (BT & 15) << 2;
    } else {                               // XX / YY upper triangles
        int t = BT - XY_BLOCKS; g = 0;
        if (t >= TRI_BLOCKS) { t -= TRI_BLOCKS; g = 1; }
        int aa = 0;
        for (;;) { int nb = (67 - aa) >> 2; if (t < nb) break; t -= nb; ++aa; }
        a = aa; b0 = aa + (t << 2);
    }
    const int b = b0 + wid;

    const float* dA = (g == 1) ? (dInc + DINC_PER) : dInc;   // row paths
    const float* dB = (g == 0) ? dInc : (dInc + DINC_PER);   // col paths

    // stage the block-uniform dX path into LDS (all 256 threads, then sync)
    {
        const float4* Ap = (const float4*)(dA + a * 2032);   // 508 float4
        const int tid = threadIdx.x;
        Xs4[tid] = Ap[tid];
        if (tid + 256 < 508) Xs4[tid + 256] = Ap[tid + 256];
    }
    __syncthreads();

    float acc = 0.0f;
    if (g == 2 || b <= 63) {               // dead triangle waves skip compute
        const float weight = (g == 2) ? (-2.0f / 4096.0f)
                                      : ((a == b ? 1.0f : 2.0f) / 4096.0f);
        const float* Qb = dB + b * 2032;
        float* cb = colbuf[wid];
        const bool last = (lane == 63);

        // K-matrix: K[r][c], c=0..127, K[0][.]=K[.][0]=1.
        // inc(r, c-1) = dX[r] . dY[c-1];  per row:
        //   d_l = K[r][c] + K[r][c-1]*(inc-1);  K[r+1][c] = seed + scan(d).

        // ---------- pass 0: c = lane+1 (cols 1..64) ----------
        float ya[16];
        {
            const float4* Y4 = (const float4*)(Qb + lane * 16);  // dY[lane]
#pragma unroll
            for (int q = 0; q < 4; ++q) {
                float4 v = Y4[q];
                ya[4*q+0]=v.x; ya[4*q+1]=v.y; ya[4*q+2]=v.z; ya[4*q+3]=v.w;
            }
        }
        if (last) cb[0] = 1.0f;            // K[0][64]
        float gc = 1.0f;                   // K[0][c]
#pragma unroll 2
        for (int r = 0; r < 127; ++r) {
            const float4* rp = &Xs4[4 * r];
            float s0 = -0.5f, s1 = -0.5f;
#pragma unroll
            for (int q = 0; q < 4; ++q) {
                float4 v = rp[q];
                s0 = fmaf(v.x, ya[4*q+0], s0);
                s1 = fmaf(v.y, ya[4*q+1], s1);
                s0 = fmaf(v.z, ya[4*q+2], s0);
                s1 = fmaf(v.w, ya[4*q+3], s1);
            }
            const float i0 = s0 + s1;                  // inc - 1
            const float gl = wave_shr1(gc, 1.0f);      // K[r][c-1]
            const float d  = fmaf(gl, i0, gc);
            const float S  = wave_scan_incl(d);
            gc = S + 1.0f;                             // K[r+1][c]
            if (last) cb[r + 1] = gc;                  // save K[r+1][64]
        }

        // ---------- pass 1: c = 65+lane (cols 65..127; lane 63 idle) ----
        {
            const int jr = (64 + lane < 127) ? 64 + lane : 126;  // dY row
            const float4* Y4 = (const float4*)(Qb + jr * 16);
#pragma unroll
            for (int q = 0; q < 4; ++q) {
                float4 v = Y4[q];
                ya[4*q+0]=v.x; ya[4*q+1]=v.y; ya[4*q+2]=v.z; ya[4*q+3]=v.w;
            }
        }
        gc = 1.0f;                         // K[0][c]
#pragma unroll 2
        for (int r = 0; r < 127; ++r) {
            const float e0 = cb[r];        // K[r][64]   (broadcast read2)
            const float e1 = cb[r + 1];    // K[r+1][64]
            const float4* rp = &Xs4[4 * r];
            float s0 = -0.5f, s1 = -0.5f;
#pragma unroll
            for (int q = 0; q < 4; ++q) {
                float4 v = rp[q];
                s0 = fmaf(v.x, ya[4*q+0], s0);
                s1 = fmaf(v.y, ya[4*q+1], s1);
                s0 = fmaf(v.z, ya[4*q+2], s0);
                s1 = fmaf(v.w, ya[4*q+3], s1);
            }
            const float i0 = s0 + s1;                  // inc - 1
            const float gl = wave_shr1(gc, e0);        // K[r][c-1]
            const float d  = fmaf(gl, i0, gc);
            const float S  = wave_scan_incl(d);
            gc = S + e1;                               // K[r+1][c]
        }

        // result K[127][127] lives in lane 62 (c = 65+62 = 127)
        const float kab = __builtin_bit_cast(float,
            __builtin_amdgcn_readlane(__builtin_bit_cast(int, gc), 62));
        acc = weight * kab;
    }

    // fused reduction: 4 waves -> LDS -> one atomic per block
    if (lane == 0) red[wid] = acc;
    __syncthreads();
    if (threadIdx.x == 0)
        atomicAdd(out, (red[0] + red[1]) + (red[2] + red[3]));
}

__global__ __launch_bounds__(256) void sig_reduce2(
    const float* __restrict__ v, float* __restrict__ out, int n)
{
    __shared__ float red[256];
    float s = 0.0f;
    for (int i = threadIdx.x; i < n; i += 256) s += v[i];
    red[threadIdx.x] = s;
    __syncthreads();
    for (int st = 128; st > 0; st >>= 1) {
        if (threadIdx.x < st) red[threadIdx.x] += red[threadIdx.x + st];
        __syncthreads();
    }
    if (threadIdx.x == 0) out[0] = red[0];
}

// ---- fallback (ws too small for increment staging): round-1 kernel ----
__global__ __launch_bounds__(64) void sig_pde_kernel(
    const float* __restrict__ X, const float* __restrict__ Y,
    float* __restrict__ ws)
{
    __shared__ float Xs[2048];
    const int T = blockIdx.x;
    const int g = T >> 12;
    const int t = T & 4095;
    const int a = t >> 6, b = t & 63;
    const int lane = threadIdx.x;
    if (g < 2 && a > b) { if (lane == 0) ws[T] = 0.0f; return; }
    const float* P = (g == 1) ? Y : X;
    const float* Q = (g == 0) ? X : Y;
    const float weight = (g == 2) ? (-2.0f / 4096.0f)
                                  : ((a == b ? 1.0f : 2.0f) / 4096.0f);
    {
        const float4* Pa = (const float4*)(P + a * 2048);
        float4* Xs4 = (float4*)Xs;
#pragma unroll
        for (int k = 0; k < 8; ++k) Xs4[lane + (k << 6)] = Pa[lane + (k << 6)];
    }
    __syncthreads();
    {
        float tmp[32];
#pragma unroll
        for (int k = 0; k < 32; ++k) {
            int idx = lane + (k << 6);
            tmp[k] = (idx < 2032) ? (Xs[idx + 16] - Xs[idx]) : 0.0f;
        }
        __syncthreads();
#pragma unroll
        for (int k = 0; k < 32; ++k) {
            int idx = lane + (k << 6);
            if (idx < 2032) Xs[idx] = tmp[k];
        }
    }
    __syncthreads();
    float y0[16], y1[16];
    {
        const float* Qb = Q + b * 2048;
        const int r0 = lane << 1;
        const int r2 = (r0 + 2 > 127) ? 127 : (r0 + 2);
        const float4* A4 = (const float4*)(Qb + r0 * 16);
        const float4* B4 = (const float4*)(Qb + (r0 + 1) * 16);
        const float4* C4 = (const float4*)(Qb + r2 * 16);
#pragma unroll
        for (int q = 0; q < 4; ++q) {
            float4 ra = A4[q], rb = B4[q], rc = C4[q];
            y0[4*q+0] = rb.x - ra.x;  y1[4*q+0] = rc.x - rb.x;
            y0[4*q+1] = rb.y - ra.y;  y1[4*q+1] = rc.y - rb.y;
            y0[4*q+2] = rb.z - ra.z;  y1[4*q+2] = rc.z - rb.z;
            y0[4*q+3] = rb.w - ra.w;  y1[4*q+3] = rc.w - rb.w;
        }
    }
    float g_lo = 1.0f, g_hi = 1.0f;
    const bool last = (lane == 63);
    for (int r = 0; r < 127; ++r) {
        const float* xrow = Xs + r * 16;
        float s0 = -0.5f, s1 = -0.5f, t0 = -0.5f, t1 = -0.5f;
#pragma unroll
        for (int d = 0; d < 16; d += 2) {
            s0 = fmaf(xrow[d], y0[d], s0);   s1 = fmaf(xrow[d+1], y0[d+1], s1);
            t0 = fmaf(xrow[d], y1[d], t0);   t1 = fmaf(xrow[d+1], y1[d+1], t1);
        }
        const float i0 = s0 + s1, i1 = t0 + t1;
        const float gl = wave_shr1(g_hi, 1.0f);
        const float c0 = fmaf(gl, i0, g_lo);
        const float c1 = last ? 0.0f : fmaf(g_lo, i1, g_hi);
        const float S = wave_scan_incl(c0 + c1);
        g_lo = (S - c1) + 1.0f;
        g_hi = S + 1.0f;
    }
    const float kab = __builtin_bit_cast(float,
        __builtin_amdgcn_readlane(__builtin_bit_cast(int, g_lo), 63));
    if (lane == 0) ws[T] = weight * kab;
}

extern "C" void kernel_launch(void* const* d_in, const int* in_sizes, int n_in,
                              void* d_out, int out_size, void* d_ws, size_t ws_size,
                              hipStream_t stream) {
    const float* X = (const float*)d_in[0];
    const float* Y = (const float*)d_in[1];
    float* out = (float*)d_out;
    float* ws  = (float*)d_ws;

    const size_t need = (size_t)(2 * DINC_PER) * sizeof(float);
    if (ws_size >= need) {
        sig_diff<<<254, 256, 0, stream>>>(X, Y, ws, out);
        sig_pde10<<<NBT, 256, 0, stream>>>(ws, out);
    } else {
        sig_pde_kernel<<<12288, 64, 0, stream>>>(X, Y, ws);
        sig_reduce2<<<1, 256, 0, stream>>>(ws, out, 12288);
    }
}

// Round 10
// 133.929 us; speedup vs baseline: 1.1866x; 1.1866x over previous
//
#include <hip/hip_runtime.h>

// Signature-kernel MMD via Goursat PDE — round 11.
// Round-10 postmortem closed the model: combining r8 (72% VALUBusy,
// ~155 cy/row apparent) + r10 (95%, 129) + m07 (scalar FMA 103 TF = 66%
// of the 2.4GHz peak) => sustained VALU clock ~1.68 GHz, DPP ~5cy. At the
// real clock r8's issue = 64 fma + 12 misc + 7 DPP*5 ~= 111 cy/row ->
// issue-wall 68us = exactly its measured 0.72*92. r8 is issue-EFFICIENT;
// the 28% gap is stall exposure from per-row strided ya/yb gathers. r4
// (pins, cap 128) was the accidentally-resident kernel: issue 70us ~= the
// resident floor, lost only to occupancy-4 exposure.
// Round-11 = r8 verbatim + ONE change: pins + __launch_bounds__(256,7)
// (cap ~72: demand ~62-66 fits -> resident dY, occupancy 7/SIMD).
// The untested {pins x moderate-cap x block-decode} cell. Clean A/B vs r8.
// Tripwire: WRITE_SIZE >= 1MB = spill -> cap too tight, fall back to 6.

#define XY_BLOCKS 1024
#define TRI_BLOCKS 544
#define NBT (XY_BLOCKS + 2 * TRI_BLOCKS)        // 2112 blocks
#define DINC_PER 130048                         // 64*127*16 floats

template <int C, int RM, int BM, bool BC>
__device__ __forceinline__ float dpp0(float x) {
    return __builtin_bit_cast(float, __builtin_amdgcn_update_dpp(
        0, __builtin_bit_cast(int, x), C, RM, BM, BC));
}

// 64-lane inclusive prefix sum, pure VALU (6 dependent adds).
__device__ __forceinline__ float wave_scan_incl(float v) {
    v += dpp0<0x111, 0xf, 0xf, true>(v);   // row_shr:1
    v += dpp0<0x112, 0xf, 0xf, true>(v);   // row_shr:2
    v += dpp0<0x114, 0xf, 0xf, true>(v);   // row_shr:4
    v += dpp0<0x118, 0xf, 0xf, true>(v);   // row_shr:8
    v += dpp0<0x142, 0xa, 0xf, false>(v);  // row_bcast:15 -> rows 1,3
    v += dpp0<0x143, 0xc, 0xf, false>(v);  // row_bcast:31 -> rows 2,3
    return v;
}

// lane l gets lane l-1's x; lane 0 gets `oldv`.
__device__ __forceinline__ float wave_shr1(float x, float oldv) {
    return __builtin_bit_cast(float, __builtin_amdgcn_update_dpp(
        __builtin_bit_cast(int, oldv), __builtin_bit_cast(int, x),
        0x138, 0xf, 0xf, false));          // wave_shr:1
}

// ---- kernel 1: path increments X,Y -> ws (dX at 0, dY at DINC_PER) ----
// (r8 version, pitch 2032 per path) + zeroes out[0] for fused reduce.
__global__ __launch_bounds__(256) void sig_diff(
    const float* __restrict__ X, const float* __restrict__ Y,
    float* __restrict__ dInc, float* __restrict__ out)
{
    if (blockIdx.x == 0 && threadIdx.x == 0) out[0] = 0.0f;
    int i = blockIdx.x * 256 + threadIdx.x;   // float4 id, 65024 total
    if (i >= 65024) return;
    int which = (i >= 32512) ? 1 : 0;
    int j = i - which * 32512;
    int a = j / 508;                          // 127*4 float4 per path
    int rq = j - a * 508;                     // r*4 + q
    const float* S = which ? Y : X;
    const float4* p = (const float4*)(S + a * 2048) + rq;
    float4 v0 = p[0], v1 = p[4];              // +16 floats = next row
    float4 d;
    d.x = v1.x - v0.x; d.y = v1.y - v0.y;
    d.z = v1.z - v0.z; d.w = v1.w - v0.w;
    ((float4*)dInc)[i] = d;
}

// ---- kernel 2: PDE. 2112 blocks * 4 waves, one (g,a,b0) per block. ----
__global__ __launch_bounds__(256, 7) void sig_pde11(
    const float* __restrict__ dInc, float* __restrict__ out)
{
    __shared__ float4 Xs4[508];            // dX path of row-index a (8128 B)
    __shared__ float red[4];
    const int wid  = threadIdx.x >> 6;
    const int lane = threadIdx.x & 63;
    const int BT   = blockIdx.x;

    // block-uniform decode -> (gram g, a, b0); b = b0 + wave id
    int g, a, b0;
    if (BT < XY_BLOCKS) {                  // XY: dense 64x64
        g = 2; a = BT >> 4; b0 = (BT & 15) << 2;
    } else {                               // XX / YY upper triangles
        int t = BT - XY_BLOCKS; g = 0;
        if (t >= TRI_BLOCKS) { t -= TRI_BLOCKS; g = 1; }
        int aa = 0;
        for (;;) { int nb = (67 - aa) >> 2; if (t < nb) break; t -= nb; ++aa; }
        a = aa; b0 = aa + (t << 2);
    }
    const int b = b0 + wid;

    const float* dA = (g == 1) ? (dInc + DINC_PER) : dInc;   // row paths
    const float* dB = (g == 0) ? dInc : (dInc + DINC_PER);   // col paths

    // stage the block-uniform dX path into LDS (all 256 threads, then sync)
    {
        const float4* Ap = (const float4*)(dA + a * 2032);   // 508 float4
        const int tid = threadIdx.x;
        Xs4[tid] = Ap[tid];
        if (tid + 256 < 508) Xs4[tid + 256] = Ap[tid + 256];
    }
    __syncthreads();

    float acc = 0.0f;
    if (g == 2 || b <= 63) {               // dead triangle waves skip compute
        const float weight = (g == 2) ? (-2.0f / 4096.0f)
                                      : ((a == b ? 1.0f : 2.0f) / 4096.0f);

        // per-lane dY rows j=2l, 2l+1 (lane 63's 2nd row masked via c1)
        float ya[16], yb_[16];
        {
            const float* Qb = dB + b * 2032;
            const int j0 = lane << 1;
            const int j1 = (j0 + 1 < 127) ? j0 + 1 : 126;
            const float4* A4 = (const float4*)(Qb + j0 * 16);
            const float4* B4 = (const float4*)(Qb + j1 * 16);
#pragma unroll
            for (int q = 0; q < 4; ++q) {
                float4 va = A4[q], vb = B4[q];
                ya[4*q+0]=va.x;  ya[4*q+1]=va.y;  ya[4*q+2]=va.z;  ya[4*q+3]=va.w;
                yb_[4*q+0]=vb.x; yb_[4*q+1]=vb.y; yb_[4*q+2]=vb.z; yb_[4*q+3]=vb.w;
            }
        }
        // Pin the 32 dY floats into VGPRs: forbids the per-row strided
        // gather remat (the 28% stall). Cap 72 has room (demand ~62-66) —
        // the r4-proven safe pattern, now at occupancy 7 instead of 4.
#pragma unroll
        for (int d = 0; d < 16; ++d)
            asm volatile("" : "+v"(ya[d]), "+v"(yb_[d]));

        float g_lo = 1.0f, g_hi = 1.0f;    // G[r][2l+1], G[r][2l+2]
        const bool last = (lane == 63);

#pragma unroll 1
        for (int r = 0; r < 127; ++r) {
            // broadcast row read: 4x ds_read_b128, uniform address
            float xr[16];
#pragma unroll
            for (int q = 0; q < 4; ++q) {
                float4 v = Xs4[4*r + q];
                xr[4*q+0]=v.x; xr[4*q+1]=v.y; xr[4*q+2]=v.z; xr[4*q+3]=v.w;
            }
            // inc - 1 via accumulators seeded with -0.5 each (2 chains/dot)
            float s0 = -0.5f, s1 = -0.5f, t0 = -0.5f, t1 = -0.5f;
#pragma unroll
            for (int d = 0; d < 16; d += 2) {
                s0 = fmaf(xr[d], ya[d], s0);    s1 = fmaf(xr[d+1], ya[d+1], s1);
                t0 = fmaf(xr[d], yb_[d], t0);   t1 = fmaf(xr[d+1], yb_[d+1], t1);
            }
            const float i0 = s0 + s1;          // inc(r, 2l)   - 1
            const float i1 = t0 + t1;          // inc(r, 2l+1) - 1

            const float gl = wave_shr1(g_hi, 1.0f);     // G[r][2l], lane0->1
            const float c0 = fmaf(gl, i0, g_lo);
            const float c1 = last ? 0.0f : fmaf(g_lo, i1, g_hi);
            const float S = wave_scan_incl(c0 + c1);
            g_lo = (S - c1) + 1.0f;
            g_hi = S + 1.0f;
        }

        const float kab = __builtin_bit_cast(float,
            __builtin_amdgcn_readlane(__builtin_bit_cast(int, g_lo), 63));
        acc = weight * kab;
    }

    // fused reduction: 4 waves -> LDS -> one atomic per block
    if (lane == 0) red[wid] = acc;
    __syncthreads();
    if (threadIdx.x == 0)
        atomicAdd(out, (red[0] + red[1]) + (red[2] + red[3]));
}

__global__ __launch_bounds__(256) void sig_reduce2(
    const float* __restrict__ v, float* __restrict__ out, int n)
{
    __shared__ float red[256];
    float s = 0.0f;
    for (int i = threadIdx.x; i < n; i += 256) s += v[i];
    red[threadIdx.x] = s;
    __syncthreads();
    for (int st = 128; st > 0; st >>= 1) {
        if (threadIdx.x < st) red[threadIdx.x] += red[threadIdx.x + st];
        __syncthreads();
    }
    if (threadIdx.x == 0) out[0] = red[0];
}

// ---- fallback (ws too small for increment staging): round-1 kernel ----
__global__ __launch_bounds__(64) void sig_pde_kernel(
    const float* __restrict__ X, const float* __restrict__ Y,
    float* __restrict__ ws)
{
    __shared__ float Xs[2048];
    const int T = blockIdx.x;
    const int g = T >> 12;
    const int t = T & 4095;
    const int a = t >> 6, b = t & 63;
    const int lane = threadIdx.x;
    if (g < 2 && a > b) { if (lane == 0) ws[T] = 0.0f; return; }
    const float* P = (g == 1) ? Y : X;
    const float* Q = (g == 0) ? X : Y;
    const float weight = (g == 2) ? (-2.0f / 4096.0f)
                                  : ((a == b ? 1.0f : 2.0f) / 4096.0f);
    {
        const float4* Pa = (const float4*)(P + a * 2048);
        float4* Xs4 = (float4*)Xs;
#pragma unroll
        for (int k = 0; k < 8; ++k) Xs4[lane + (k << 6)] = Pa[lane + (k << 6)];
    }
    __syncthreads();
    {
        float tmp[32];
#pragma unroll
        for (int k = 0; k < 32; ++k) {
            int idx = lane + (k << 6);
            tmp[k] = (idx < 2032) ? (Xs[idx + 16] - Xs[idx]) : 0.0f;
        }
        __syncthreads();
#pragma unroll
        for (int k = 0; k < 32; ++k) {
            int idx = lane + (k << 6);
            if (idx < 2032) Xs[idx] = tmp[k];
        }
    }
    __syncthreads();
    float y0[16], y1[16];
    {
        const float* Qb = Q + b * 2048;
        const int r0 = lane << 1;
        const int r2 = (r0 + 2 > 127) ? 127 : (r0 + 2);
        const float4* A4 = (const float4*)(Qb + r0 * 16);
        const float4* B4 = (const float4*)(Qb + (r0 + 1) * 16);
        const float4* C4 = (const float4*)(Qb + r2 * 16);
#pragma unroll
        for (int q = 0; q < 4; ++q) {
            float4 ra = A4[q], rb = B4[q], rc = C4[q];
            y0[4*q+0] = rb.x - ra.x;  y1[4*q+0] = rc.x - rb.x;
            y0[4*q+1] = rb.y - ra.y;  y1[4*q+1] = rc.y - rb.y;
            y0[4*q+2] = rb.z - ra.z;  y1[4*q+2] = rc.z - rb.z;
            y0[4*q+3] = rb.w - ra.w;  y1[4*q+3] = rc.w - rb.w;
        }
    }
    float g_lo = 1.0f, g_hi = 1.0f;
    const bool last = (lane == 63);
    for (int r = 0; r < 127; ++r) {
        const float* xrow = Xs + r * 16;
        float s0 = -0.5f, s1 = -0.5f, t0 = -0.5f, t1 = -0.5f;
#pragma unroll
        for (int d = 0; d < 16; d += 2) {
            s0 = fmaf(xrow[d], y0[d], s0);   s1 = fmaf(xrow[d+1], y0[d+1], s1);
            t0 = fmaf(xrow[d], y1[d], t0);   t1 = fmaf(xrow[d+1], y1[d+1], t1);
        }
        const float i0 = s0 + s1, i1 = t0 + t1;
        const float gl = wave_shr1(g_hi, 1.0f);
        const float c0 = fmaf(gl, i0, g_lo);
        const float c1 = last ? 0.0f : fmaf(g_lo, i1, g_hi);
        const float S = wave_scan_incl(c0 + c1);
        g_lo = (S - c1) + 1.0f;
        g_hi = S + 1.0f;
    }
    const float kab = __builtin_bit_cast(float,
        __builtin_amdgcn_readlane(__builtin_bit_cast(int, g_lo), 63));
    if (lane == 0) ws[T] = weight * kab;
}

extern "C" void kernel_launch(void* const* d_in, const int* in_sizes, int n_in,
                              void* d_out, int out_size, void* d_ws, size_t ws_size,
                              hipStream_t stream) {
    const float* X = (const float*)d_in[0];
    const float* Y = (const float*)d_in[1];
    float* out = (float*)d_out;
    float* ws  = (float*)d_ws;

    const size_t need = (size_t)(2 * DINC_PER) * sizeof(float);
    if (ws_size >= need) {
        sig_diff<<<254, 256, 0, stream>>>(X, Y, ws, out);
        sig_pde11<<<NBT, 256, 0, stream>>>(ws, out);
    } else {
        sig_pde_kernel<<<12288, 64, 0, stream>>>(X, Y, ws);
        sig_reduce2<<<1, 256, 0, stream>>>(ws, out, 12288);
    }
}